// Round 2
// baseline (762.587 us; speedup 1.0000x reference)
//
#include <hip/hip_runtime.h>
#include <math.h>

// Problem constants
#define B_    8
#define NT_   1024
#define DIM_  768
#define H_    12
#define HD_   64
#define SCALE_ 0.125f
#define T_ELEMS 6291456UL   // B*NT*DIM

typedef _Float16 half8  __attribute__((ext_vector_type(8)));
typedef _Float16 half4v __attribute__((ext_vector_type(4)));
typedef float    floatx4 __attribute__((ext_vector_type(4)));

#if __has_builtin(__builtin_amdgcn_exp2f)
#define EXP2F(x) __builtin_amdgcn_exp2f(x)
#else
#define EXP2F(x) exp2f(x)
#endif

// async global->LDS, 16B per lane; LDS dest = wave-uniform base + lane*16
#define GLD16(gp, lp) __builtin_amdgcn_global_load_lds( \
    (const __attribute__((address_space(1))) unsigned int*)(gp), \
    (__attribute__((address_space(3))) unsigned int*)(lp), 16, 0, 0)

// ---------------------------------------------------------------- conversion
__global__ void cvt4(const float* __restrict__ in, _Float16* __restrict__ out,
                     int n4) {
  int i = blockIdx.x * 256 + threadIdx.x;
  if (i < n4) {
    float4 v = ((const float4*)in)[i];
    half4v h = { (_Float16)v.x, (_Float16)v.y, (_Float16)v.z, (_Float16)v.w };
    *(half4v*)(out + 4 * (size_t)i) = h;
  }
}

// ---------------------------------------------------------------- GEMM
// m97 structure: 128x128 tile, BK=32, 4 waves (2x2), each wave 64x64 = 4x4
// frags of 16x16x32. Linear LDS + width-16 global_load_lds staging.
// C[m][n] = sum_k A[m][k]*Bt[n][k] + bias[n].
// MODE 0: fused QKV (Bt = wq;wk;wv, 2304 rows), fp16 out at outh+sel*T.
// MODE 1: fp32 out single buffer.
// XCD swizzle: nwg divisible by 8 (1152 / 384), contiguous chunk per XCD.
template<int MODE>
__global__ __launch_bounds__(256) void gemm128(
    const _Float16* __restrict__ A, const _Float16* __restrict__ Bt,
    const float* __restrict__ b0_, const float* __restrict__ b1_,
    const float* __restrict__ b2_, _Float16* __restrict__ outh,
    float* __restrict__ outf, int K)
{
  __shared__ _Float16 As[128 * 32];
  __shared__ _Float16 Bs[128 * 32];
  const int t    = threadIdx.x;
  const int w    = t >> 6, lane = t & 63;
  const int quad = lane >> 4, l16 = lane & 15;
  const int wm   = (w >> 1) * 64, wn = (w & 1) * 64;

  // XCD-aware bijective swizzle (nwg % 8 == 0)
  const int nbx = gridDim.x;
  int lin = blockIdx.y * nbx + blockIdx.x;
  const int cpx = (nbx * gridDim.y) >> 3;
  lin = (lin & 7) * cpx + (lin >> 3);
  const int m0 = (lin % nbx) * 128, n0 = (lin / nbx) * 128;

  // staging: thread t covers LDS bytes [t*16, t*16+16) = row t/4, halves (t&3)*8
  const _Float16* gA = A  + (size_t)(m0 + (t >> 2)) * K + (t & 3) * 8;
  const _Float16* gB = Bt + (size_t)(n0 + (t >> 2)) * K + (t & 3) * 8;
  _Float16* lA = As + w * 512;   // wave-uniform base (+ lane*8 halves implicit)
  _Float16* lB = Bs + w * 512;
  const size_t rowK = (size_t)64 * K;

  floatx4 acc[4][4] = {};

  for (int k0 = 0; k0 < K; k0 += 32) {
    __syncthreads();                    // prev iter ds_reads drained
    GLD16(gA + k0,        lA);          // rows 0..63
    GLD16(gA + rowK + k0, lA + 2048);   // rows 64..127
    GLD16(gB + k0,        lB);
    GLD16(gB + rowK + k0, lB + 2048);
    __syncthreads();                    // vmcnt(0) drain -> tile ready

    half8 af[4], bf[4];
#pragma unroll
    for (int i = 0; i < 4; i++)
      af[i] = *(const half8*)(As + (wm + i * 16 + l16) * 32 + quad * 8);
#pragma unroll
    for (int j = 0; j < 4; j++)
      bf[j] = *(const half8*)(Bs + (wn + j * 16 + l16) * 32 + quad * 8);
#pragma unroll
    for (int i = 0; i < 4; i++)
#pragma unroll
      for (int j = 0; j < 4; j++)
        acc[i][j] = __builtin_amdgcn_mfma_f32_16x16x32_f16(af[i], bf[j],
                                                           acc[i][j], 0, 0, 0);
  }

  // C/D layout: row = quad*4 + reg, col = lane&15  [m89/m91]
  const int sel = (MODE == 0) ? (n0 / 768) : 0;
  const float* bb = (MODE == 0)
                      ? (sel == 0 ? b0_ : (sel == 1 ? b1_ : b2_))
                      : b0_;
#pragma unroll
  for (int j = 0; j < 4; j++) {
    const int col = n0 + wn + j * 16 + l16;
    const int cl  = col - sel * 768;
    const float bv = bb[cl];
#pragma unroll
    for (int i = 0; i < 4; i++)
#pragma unroll
      for (int r = 0; r < 4; r++) {
        const int row = m0 + wm + i * 16 + quad * 4 + r;
        const float v = acc[i][j][r] + bv;
        if (MODE == 0)
          outh[(size_t)sel * T_ELEMS + (size_t)row * 768 + cl] = (_Float16)v;
        else
          outf[(size_t)row * 768 + col] = v;
      }
  }
}

// ---------------------------------------------------------------- V transpose
// Vh [b][token][dim] (head h at col h*64) -> VT [b*H+h][d][token]
// One 64(token)x64(d) tile per block.
__global__ __launch_bounds__(256) void transpose_v(
    const _Float16* __restrict__ Vh, _Float16* __restrict__ VT)
{
  __shared__ _Float16 tile[64][72];
  const int t = threadIdx.x;
  const int tt = blockIdx.x, h = blockIdx.y, b = blockIdx.z;
  const int lrow = t >> 2, lcol = (t & 3) * 16;

  const _Float16* src = Vh + ((size_t)b * NT_ + tt * 64 + lrow) * DIM_ + h * HD_;
  *(uint4*)(&tile[lrow][lcol])     = *(const uint4*)(src + lcol);
  *(uint4*)(&tile[lrow][lcol + 8]) = *(const uint4*)(src + lcol + 8);
  __syncthreads();

  alignas(16) _Float16 vh[16];
#pragma unroll
  for (int c = 0; c < 16; c++) vh[c] = tile[lcol + c][lrow];  // [token][d] -> d-row
  _Float16* dst = VT + ((size_t)(b * H_ + h) * HD_ + lrow) * NT_ + tt * 64 + lcol;
  *(uint4*)(dst)     = *(const uint4*)(vh);
  *(uint4*)(dst + 8) = *(const uint4*)(vh + 8);
}

// ---------------------------------------------------------------- attention
// One block per (qtile=64 rows, h, b); 4 waves, wave w owns q-rows
// [w*16,w*16+16). NO LDS staging of K/V: MFMA fragments are read directly
// from global (L2-resident, XCD-grouped). NO __syncthreads anywhere.
// Softmax without max-subtraction (scores are O(1)-scaled; exp2 domain,
// fp32 cannot overflow):
//   pass 1: S = QK^T, per-lane partial sums of exp2(s*C2) accumulated in
//           registers across all tiles; ONE shuffle-reduce at the end.
//   pass 2: recompute S, p = exp2(s*C2 - log2(l)); write attn, PV via MFMA
//           (P round-trips through per-wave Ps LDS for layout conversion).
__global__ __launch_bounds__(256) void attn_kernel(
    const _Float16* __restrict__ Qh, const _Float16* __restrict__ Kh,
    const _Float16* __restrict__ VT, float* __restrict__ attn_out,
    _Float16* __restrict__ Xh)
{
  __shared__ _Float16 Ps[64][72];  // per-wave rows; no cross-wave sharing

  const int t    = threadIdx.x;
  const int w    = t >> 6, lane = t & 63;
  const int quad = lane >> 4, l16 = lane & 15;

  // XCD-grouping swizzle: the 16 q-tiles of one (b,h) share an XCD slot
  const int bid  = blockIdx.x;          // 0..1535
  const int slot = bid & 7, i = bid >> 3;
  const int g    = slot + 8 * (i >> 4); // 0..95 = b*H + h
  const int qt   = i & 15;
  const int b    = g / H_, h = g % H_;
  const int q0   = qt * 64;

  const _Float16* Qb = Qh + ((size_t)b * NT_) * DIM_ + h * HD_;
  const _Float16* Kb = Kh + ((size_t)b * NT_) * DIM_ + h * HD_;
  const _Float16* Vb = VT + (size_t)g * HD_ * NT_;   // [d][token]

  // Q fragment (A-operand): row = w*16 + l16, k = ks*32 + quad*8 + j
  half8 qf[2];
  {
    const _Float16* qr = Qb + (size_t)(q0 + w * 16 + l16) * DIM_ + quad * 8;
    qf[0] = *(const half8*)(qr);
    qf[1] = *(const half8*)(qr + 32);
  }

  const float C2 = 0.18033688011112042f;  // SCALE * log2(e)

  // ---------------- pass 1: per-lane partial row sums (no max, no staging)
  float lsum[4] = {0.f, 0.f, 0.f, 0.f};
  for (int kt = 0; kt < 16; kt++) {
    const _Float16* kb = Kb + (size_t)(kt * 64 + l16) * DIM_ + quad * 8;
    floatx4 s[4] = {};
#pragma unroll
    for (int ks = 0; ks < 2; ks++)
#pragma unroll
      for (int j = 0; j < 4; j++) {
        half8 bk = *(const half8*)(kb + (size_t)(j * 16) * DIM_ + ks * 32);
        s[j] = __builtin_amdgcn_mfma_f32_16x16x32_f16(qf[ks], bk, s[j], 0, 0, 0);
      }
#pragma unroll
    for (int j = 0; j < 4; j++)
#pragma unroll
      for (int r = 0; r < 4; r++)
        lsum[r] += EXP2F(s[j][r] * C2);
  }

  // single deferred reduce over the 16 key-lanes; mb = log2(row sum)
  float mb[4];
#pragma unroll
  for (int r = 0; r < 4; r++) {
    float ts = lsum[r];
    for (int off = 1; off < 16; off <<= 1) ts += __shfl_xor(ts, off, 64);
    mb[r] = log2f(ts);
  }

  // ---------------- pass 2: recompute S, normalize, write attn, O = P @ V
  floatx4 oacc[4] = {};
  float* attn_b = attn_out + ((size_t)g * NT_ + q0) * NT_;

  for (int kt = 0; kt < 16; kt++) {
    const _Float16* kb = Kb + (size_t)(kt * 64 + l16) * DIM_ + quad * 8;
    floatx4 s[4] = {};
#pragma unroll
    for (int ks = 0; ks < 2; ks++)
#pragma unroll
      for (int j = 0; j < 4; j++) {
        half8 bk = *(const half8*)(kb + (size_t)(j * 16) * DIM_ + ks * 32);
        s[j] = __builtin_amdgcn_mfma_f32_16x16x32_f16(qf[ks], bk, s[j], 0, 0, 0);
      }

    // issue V^T fragment loads early; latency hides under softmax VALU
    half8 bv[2][4];
    const _Float16* vb = Vb + (size_t)l16 * NT_ + kt * 64 + quad * 8;
#pragma unroll
    for (int ks = 0; ks < 2; ks++)
#pragma unroll
      for (int j2 = 0; j2 < 4; j2++)
        bv[ks][j2] = *(const half8*)(vb + (size_t)(j2 * 16) * NT_ + ks * 32);

    // p = exp2(s*C2 - log2(l)); write attn (fp32), stage P (fp16)
#pragma unroll
    for (int j = 0; j < 4; j++)
#pragma unroll
      for (int r = 0; r < 4; r++) {
        const float p = EXP2F(fmaf(s[j][r], C2, -mb[r]));
        const int qr = w * 16 + quad * 4 + r;
        attn_b[(size_t)qr * NT_ + kt * 64 + j * 16 + l16] = p;
        Ps[qr][j * 16 + l16] = (_Float16)p;
      }
    // Ps rows [w*16,w*16+16) written AND read only by wave w -> no barrier

#pragma unroll
    for (int ks = 0; ks < 2; ks++) {
      half8 pa = *(const half8*)(&Ps[w * 16 + l16][ks * 32 + quad * 8]);
#pragma unroll
      for (int j2 = 0; j2 < 4; j2++)
        oacc[j2] = __builtin_amdgcn_mfma_f32_16x16x32_f16(pa, bv[ks][j2],
                                                          oacc[j2], 0, 0, 0);
    }
  }

  // write X (fp16, [B,NT,DIM] with head offset) for the output projection
#pragma unroll
  for (int j2 = 0; j2 < 4; j2++)
#pragma unroll
    for (int r = 0; r < 4; r++) {
      const int qr = q0 + w * 16 + quad * 4 + r;
      Xh[((size_t)b * NT_ + qr) * DIM_ + h * HD_ + j2 * 16 + l16] = (_Float16)oacc[j2][r];
    }
}

// ---------------------------------------------------------------- launch
extern "C" void kernel_launch(void* const* d_in, const int* in_sizes, int n_in,
                              void* d_out, int out_size, void* d_ws, size_t ws_size,
                              hipStream_t stream) {
  const float* tfeat = (const float*)d_in[0];
  const float* wq    = (const float*)d_in[1];
  const float* bq    = (const float*)d_in[2];
  const float* wk    = (const float*)d_in[3];
  const float* bk    = (const float*)d_in[4];
  const float* wv    = (const float*)d_in[5];
  const float* bv    = (const float*)d_in[6];
  const float* wp    = (const float*)d_in[7];
  const float* bp    = (const float*)d_in[8];
  float* out = (float*)d_out;

  const size_t T = T_ELEMS;                   // 6,291,456
  const size_t W = (size_t)DIM_ * DIM_;       // 589,824

  _Float16* ws  = (_Float16*)d_ws;
  _Float16* tfh = ws;
  _Float16* wqh = ws + T;          // wq;wk;wv contiguous -> fused Bt (2304 rows)
  _Float16* wkh = ws + T + W;
  _Float16* wvh = ws + T + 2 * W;
  _Float16* wph = ws + T + 3 * W;
  _Float16* Qh  = ws + T + 4 * W;  // Q;K;V contiguous (GEMM sel offsets)
  _Float16* Kh  = Qh + T;
  _Float16* Vh  = Kh + T;
  _Float16* Xh  = Vh + T;
  _Float16* VTt = Xh + T;          // V transposed: [b*H+h][d][token]

  cvt4<<<(int)(T / 4 / 256), 256, 0, stream>>>(tfeat, tfh, (int)(T / 4));
  cvt4<<<(int)(W / 4 / 256), 256, 0, stream>>>(wq, wqh, (int)(W / 4));
  cvt4<<<(int)(W / 4 / 256), 256, 0, stream>>>(wk, wkh, (int)(W / 4));
  cvt4<<<(int)(W / 4 / 256), 256, 0, stream>>>(wv, wvh, (int)(W / 4));
  cvt4<<<(int)(W / 4 / 256), 256, 0, stream>>>(wp, wph, (int)(W / 4));

  // fused QKV: M=8192, N=3*768=2304, K=768
  gemm128<0><<<dim3(64, 18), 256, 0, stream>>>(tfh, wqh, bq, bk, bv, Qh, nullptr, 768);

  transpose_v<<<dim3(16, 12, 8), 256, 0, stream>>>(Vh, VTt);

  attn_kernel<<<1536, 256, 0, stream>>>(Qh, Kh, VTt, out + T, Xh);

  // projection: M=8192, N=768, K=768, fp32 out
  gemm128<1><<<dim3(64, 6), 256, 0, stream>>>(Xh, wph, bp, nullptr, nullptr, nullptr, out, 768);
}

// Round 3
// 625.461 us; speedup vs baseline: 1.2192x; 1.2192x over previous
//
#include <hip/hip_runtime.h>
#include <math.h>

// Problem constants
#define B_    8
#define NT_   1024
#define DIM_  768
#define H_    12
#define HD_   64
#define T_ELEMS 6291456UL   // B*NT*DIM

typedef _Float16 half8  __attribute__((ext_vector_type(8)));
typedef _Float16 half4v __attribute__((ext_vector_type(4)));
typedef float    floatx4 __attribute__((ext_vector_type(4)));

#if __has_builtin(__builtin_amdgcn_exp2f)
#define EXP2F(x) __builtin_amdgcn_exp2f(x)
#else
#define EXP2F(x) exp2f(x)
#endif

// async global->LDS, 16B per lane; LDS dest = wave-uniform base + lane*16
#define GLD16(gp, lp) __builtin_amdgcn_global_load_lds( \
    (const __attribute__((address_space(1))) unsigned int*)(gp), \
    (__attribute__((address_space(3))) unsigned int*)(lp), 16, 0, 0)

#define MFMA16(a, b, c) __builtin_amdgcn_mfma_f32_16x16x32_f16((a), (b), (c), 0, 0, 0)

// ---------------------------------------------------------------- conversion
__global__ void cvt4(const float* __restrict__ in, _Float16* __restrict__ out,
                     int n4) {
  int i = blockIdx.x * 256 + threadIdx.x;
  if (i < n4) {
    float4 v = ((const float4*)in)[i];
    half4v h = { (_Float16)v.x, (_Float16)v.y, (_Float16)v.z, (_Float16)v.w };
    *(half4v*)(out + 4 * (size_t)i) = h;
  }
}

// 4 weight matrices (sources separate, dests contiguous) in one launch
__global__ void cvtW4(const float* __restrict__ w0, const float* __restrict__ w1,
                      const float* __restrict__ w2, const float* __restrict__ w3,
                      _Float16* __restrict__ out) {
  const int n4 = (DIM_ * DIM_) / 4;          // per matrix
  int i = blockIdx.x * 256 + threadIdx.x;    // 0 .. 4*n4
  const int seg = i / n4, off = i - seg * n4;
  const float* src = (seg == 0) ? w0 : (seg == 1) ? w1 : (seg == 2) ? w2 : w3;
  float4 v = ((const float4*)src)[off];
  half4v h = { (_Float16)v.x, (_Float16)v.y, (_Float16)v.z, (_Float16)v.w };
  *(half4v*)(out + 4 * (size_t)i) = h;
}

// ---------------------------------------------------------------- GEMM
// m97 structure (round-1 proven): 128x128 tile, BK=32, 4 waves, 4x4 frags.
// Linear LDS + width-16 global_load_lds. C[m][n]=sum_k A[m][k]*Bt[n][k]+bias.
// MODE 0: fused QKV (Bt = wq;wk;wv), fp16 out at outh+sel*T. MODE 1: fp32 out.
template<int MODE>
__global__ __launch_bounds__(256) void gemm128(
    const _Float16* __restrict__ A, const _Float16* __restrict__ Bt,
    const float* __restrict__ b0_, const float* __restrict__ b1_,
    const float* __restrict__ b2_, _Float16* __restrict__ outh,
    float* __restrict__ outf, int K)
{
  __shared__ _Float16 As[128 * 32];
  __shared__ _Float16 Bs[128 * 32];
  const int t    = threadIdx.x;
  const int w    = t >> 6, lane = t & 63;
  const int quad = lane >> 4, l16 = lane & 15;
  const int wm   = (w >> 1) * 64, wn = (w & 1) * 64;
  const int m0   = blockIdx.x * 128, n0 = blockIdx.y * 128;

  const _Float16* gA = A  + (size_t)(m0 + (t >> 2)) * K + (t & 3) * 8;
  const _Float16* gB = Bt + (size_t)(n0 + (t >> 2)) * K + (t & 3) * 8;
  _Float16* lA = As + w * 512;
  _Float16* lB = Bs + w * 512;
  const size_t rowK = (size_t)64 * K;

  floatx4 acc[4][4] = {};

  for (int k0 = 0; k0 < K; k0 += 32) {
    __syncthreads();
    GLD16(gA + k0,        lA);
    GLD16(gA + rowK + k0, lA + 2048);
    GLD16(gB + k0,        lB);
    GLD16(gB + rowK + k0, lB + 2048);
    __syncthreads();

    half8 af[4], bf[4];
#pragma unroll
    for (int i = 0; i < 4; i++)
      af[i] = *(const half8*)(As + (wm + i * 16 + l16) * 32 + quad * 8);
#pragma unroll
    for (int j = 0; j < 4; j++)
      bf[j] = *(const half8*)(Bs + (wn + j * 16 + l16) * 32 + quad * 8);
#pragma unroll
    for (int i = 0; i < 4; i++)
#pragma unroll
      for (int j = 0; j < 4; j++)
        acc[i][j] = MFMA16(af[i], bf[j], acc[i][j]);
  }

  const int sel = (MODE == 0) ? (n0 / 768) : 0;
  const float* bb = (MODE == 0)
                      ? (sel == 0 ? b0_ : (sel == 1 ? b1_ : b2_))
                      : b0_;
#pragma unroll
  for (int j = 0; j < 4; j++) {
    const int col = n0 + wn + j * 16 + l16;
    const int cl  = col - sel * 768;
    const float bv = bb[cl];
#pragma unroll
    for (int i = 0; i < 4; i++)
#pragma unroll
      for (int r = 0; r < 4; r++) {
        const int row = m0 + wm + i * 16 + quad * 4 + r;
        const float v = acc[i][j][r] + bv;
        if (MODE == 0)
          outh[(size_t)sel * T_ELEMS + (size_t)row * 768 + cl] = (_Float16)v;
        else
          outf[(size_t)row * 768 + col] = v;
      }
  }
}

// ---------------------------------------------------------------- V transpose
// Vh [b][token][dim] (head h at col h*64) -> VT [b*H+h][d][token]
__global__ __launch_bounds__(256) void transpose_v(
    const _Float16* __restrict__ Vh, _Float16* __restrict__ VT)
{
  __shared__ _Float16 tile[64][72];
  const int t = threadIdx.x;
  const int tt = blockIdx.x, h = blockIdx.y, b = blockIdx.z;
  const int lrow = t >> 2, lcol = (t & 3) * 16;

  const _Float16* src = Vh + ((size_t)b * NT_ + tt * 64 + lrow) * DIM_ + h * HD_;
  *(uint4*)(&tile[lrow][lcol])     = *(const uint4*)(src + lcol);
  *(uint4*)(&tile[lrow][lcol + 8]) = *(const uint4*)(src + lcol + 8);
  __syncthreads();

  alignas(16) _Float16 vh[16];
#pragma unroll
  for (int c = 0; c < 16; c++) vh[c] = tile[lcol + c][lrow];
  _Float16* dst = VT + ((size_t)(b * H_ + h) * HD_ + lrow) * NT_ + tt * 64 + lcol;
  *(uint4*)(dst)     = *(const uint4*)(vh);
  *(uint4*)(dst + 8) = *(const uint4*)(vh + 8);
}

// ---------------------------------------------------------------- attention
// One block per (qtile=64, g=b*H+h); 4 waves, wave w owns q rows [w*16,w*16+16).
// K tile (64x64 f16, 8KB) double-buffered in LDS via global_load_lds with a
// single barrier per tile (T3-minimum 2-phase: STAGE(next) -> compute(cur) ->
// barrier). LDS content is XOR-swizzled (granule ^= row&7) with the inverse
// permutation applied to the GLOBAL source address (rule #21), so ds_read_b128
// fragment reads are bank-conflict-free. V fragments direct from pre-transposed
// VT (issued at loop top, ~600cy slack). Softmax without max-subtraction
// (scores ~N(0,1); exp2 domain cannot overflow): pass 1 accumulates per-lane
// partial sums in registers, ONE shuffle reduce total; pass 2 recomputes S and
// emits p = exp2(s*C2 - log2(l)). attn/X stores are non-temporal (keep K/V in L2).
__global__ __launch_bounds__(256) void attn_kernel(
    const _Float16* __restrict__ Qh, const _Float16* __restrict__ Kh,
    const _Float16* __restrict__ VT, float* __restrict__ attn_out,
    _Float16* __restrict__ Xh)
{
  __shared__ _Float16 Ks[2 * 4096];   // 2 x (64 rows x 64 halves), swizzled
  __shared__ _Float16 Ps[64][72];     // per-wave rows; no cross-wave sharing

  const int t    = threadIdx.x;
  const int w    = t >> 6, lane = t & 63;
  const int quad = lane >> 4, l16 = lane & 15;

  // XCD-grouping: the 16 q-tiles of one (b,h) share an XCD slot
  const int bid  = blockIdx.x;          // 0..1535
  const int slot = bid & 7, i = bid >> 3;
  const int g    = slot + 8 * (i >> 4); // 0..95 = b*H + h
  const int qt   = i & 15;
  const int b    = g / H_, h = g % H_;
  const int q0   = qt * 64;

  const _Float16* Qb = Qh + ((size_t)b * NT_) * DIM_ + h * HD_;
  const _Float16* Kb = Kh + ((size_t)b * NT_) * DIM_ + h * HD_;
  const _Float16* Vb = VT + (size_t)g * HD_ * NT_;   // [d][token]

  // --- K staging addresses. Lane covers 16B: local row = w*8 + (lane>>3)
  // (rounds a=0,1 add 32 rows), LDS slot = lane&7 (linear). Source granule is
  // pre-swizzled: (lane&7) ^ (lane>>3)  -- XOR involution, row&7 == lane>>3.
  const int krl   = (w << 3) + (lane >> 3);
  const int kgran = (lane & 7) ^ (lane >> 3);
  const _Float16* Kstage = Kb + (size_t)krl * DIM_ + kgran * 8;
  _Float16* kdst = Ks + (w << 9);   // wave-uniform; +c*4096 +a*2048

#define STAGE_K(kt, c) do { \
    const _Float16* s_ = Kstage + (size_t)(kt) * 64 * DIM_; \
    GLD16(s_,                     kdst + (c) * 4096); \
    GLD16(s_ + (size_t)32 * DIM_, kdst + (c) * 4096 + 2048); \
  } while (0)

  // swizzled read offsets: halves = row*64 + ((gran ^ (row&7))<<3),
  // row = j*16+l16, gran = ks*4+quad
  const int rsw0 = ((quad      ^ (l16 & 7)) << 3);  // ks=0
  const int rsw1 = (((4 + quad) ^ (l16 & 7)) << 3); // ks=1

  // Q fragment (A-operand): row = w*16 + l16, k = ks*32 + quad*8 + j
  half8 qf[2];
  {
    const _Float16* qr = Qb + (size_t)(q0 + w * 16 + l16) * DIM_ + quad * 8;
    qf[0] = *(const half8*)(qr);
    qf[1] = *(const half8*)(qr + 32);
  }

  const float C2 = 0.18033688011112042f;  // SCALE * log2(e)

  // ---------------- pass 1: per-lane partial row sums
  float lsum[4] = {0.f, 0.f, 0.f, 0.f};
  STAGE_K(0, 0);
  __syncthreads();
  for (int kt = 0; kt < 16; kt++) {
    const int cur = kt & 1;
    if (kt < 15) STAGE_K(kt + 1, cur ^ 1);
    const _Float16* kb = Ks + cur * 4096;
    floatx4 s[4] = {};
#pragma unroll
    for (int j = 0; j < 4; j++) {
      const int rb = (j * 16 + l16) * 64;
      half8 k0 = *(const half8*)(kb + rb + rsw0);
      half8 k1 = *(const half8*)(kb + rb + rsw1);
      s[j] = MFMA16(qf[0], k0, s[j]);
      s[j] = MFMA16(qf[1], k1, s[j]);
    }
#pragma unroll
    for (int j = 0; j < 4; j++)
#pragma unroll
      for (int r = 0; r < 4; r++)
        lsum[r] += EXP2F(s[j][r] * C2);
    __syncthreads();   // next tile staged + all waves done with cur
  }

  // single deferred reduce over the 16 key-lanes (within quad group)
  float mb[4];
#pragma unroll
  for (int r = 0; r < 4; r++) {
    float ts = lsum[r];
    for (int off = 1; off < 16; off <<= 1) ts += __shfl_xor(ts, off, 64);
    mb[r] = log2f(ts);
  }

  // ---------------- pass 2: recompute S, normalize, write attn, O = P @ V
  floatx4 oacc[4] = {};
  float* attn_b = attn_out + ((size_t)g * NT_ + q0) * NT_;

  STAGE_K(0, 0);
  __syncthreads();
  for (int kt = 0; kt < 16; kt++) {
    const int cur = kt & 1;
    if (kt < 15) STAGE_K(kt + 1, cur ^ 1);

    // V^T fragments direct from global, issued early (consumed after softmax)
    half8 bv[2][4];
    const _Float16* vb = Vb + (size_t)l16 * NT_ + kt * 64 + quad * 8;
#pragma unroll
    for (int ks = 0; ks < 2; ks++)
#pragma unroll
      for (int j2 = 0; j2 < 4; j2++)
        bv[ks][j2] = *(const half8*)(vb + (size_t)(j2 * 16) * NT_ + ks * 32);

    const _Float16* kb = Ks + cur * 4096;
    floatx4 s[4] = {};
#pragma unroll
    for (int j = 0; j < 4; j++) {
      const int rb = (j * 16 + l16) * 64;
      half8 k0 = *(const half8*)(kb + rb + rsw0);
      half8 k1 = *(const half8*)(kb + rb + rsw1);
      s[j] = MFMA16(qf[0], k0, s[j]);
      s[j] = MFMA16(qf[1], k1, s[j]);
    }

    // p = exp2(s*C2 - log2(l)); non-temporal attn store, stage P in LDS
#pragma unroll
    for (int j = 0; j < 4; j++)
#pragma unroll
      for (int r = 0; r < 4; r++) {
        const float p = EXP2F(fmaf(s[j][r], C2, -mb[r]));
        const int qr = w * 16 + quad * 4 + r;
        __builtin_nontemporal_store(p, &attn_b[(size_t)qr * NT_ + kt * 64 + j * 16 + l16]);
        Ps[qr][j * 16 + l16] = (_Float16)p;
      }
    // Ps rows [w*16,w*16+16) written AND read only by wave w -> no barrier

#pragma unroll
    for (int ks = 0; ks < 2; ks++) {
      half8 pa = *(const half8*)(&Ps[w * 16 + l16][ks * 32 + quad * 8]);
#pragma unroll
      for (int j2 = 0; j2 < 4; j2++)
        oacc[j2] = MFMA16(pa, bv[ks][j2], oacc[j2]);
    }
    __syncthreads();   // next K tile staged + all waves done with cur
  }

  // write X (fp16) for the output projection
#pragma unroll
  for (int j2 = 0; j2 < 4; j2++)
#pragma unroll
    for (int r = 0; r < 4; r++) {
      const int qr = q0 + w * 16 + quad * 4 + r;
      __builtin_nontemporal_store((_Float16)oacc[j2][r],
          &Xh[((size_t)b * NT_ + qr) * DIM_ + h * HD_ + j2 * 16 + l16]);
    }
#undef STAGE_K
}

// ---------------------------------------------------------------- launch
extern "C" void kernel_launch(void* const* d_in, const int* in_sizes, int n_in,
                              void* d_out, int out_size, void* d_ws, size_t ws_size,
                              hipStream_t stream) {
  const float* tfeat = (const float*)d_in[0];
  const float* wq    = (const float*)d_in[1];
  const float* bq    = (const float*)d_in[2];
  const float* wk    = (const float*)d_in[3];
  const float* bk    = (const float*)d_in[4];
  const float* wv    = (const float*)d_in[5];
  const float* bv    = (const float*)d_in[6];
  const float* wp    = (const float*)d_in[7];
  const float* bp    = (const float*)d_in[8];
  float* out = (float*)d_out;

  const size_t T = T_ELEMS;                   // 6,291,456
  const size_t W = (size_t)DIM_ * DIM_;       // 589,824

  _Float16* ws  = (_Float16*)d_ws;
  _Float16* tfh = ws;
  _Float16* wqh = ws + T;          // wq;wk;wv;wp contiguous
  _Float16* wph = ws + T + 3 * W;
  _Float16* Qh  = ws + T + 4 * W;  // Q;K;V contiguous (GEMM sel offsets)
  _Float16* Kh  = Qh + T;
  _Float16* Vh  = Kh + T;
  _Float16* Xh  = Vh + T;
  _Float16* VTt = Xh + T;          // V transposed: [b*H+h][d][token]

  cvt4<<<(int)(T / 4 / 256), 256, 0, stream>>>(tfeat, tfh, (int)(T / 4));
  cvtW4<<<(int)(4 * W / 4 / 256), 256, 0, stream>>>(wq, wk, wv, wp, wqh);

  // fused QKV: M=8192, N=3*768=2304, K=768
  gemm128<0><<<dim3(64, 18), 256, 0, stream>>>(tfh, wqh, bq, bk, bv, Qh, nullptr, 768);

  transpose_v<<<dim3(16, 12, 8), 256, 0, stream>>>(Vh, VTt);

  attn_kernel<<<1536, 256, 0, stream>>>(Qh, Kh, VTt, out + T, Xh);

  // projection: M=8192, N=768, K=768, fp32 out
  gemm128<1><<<dim3(64, 6), 256, 0, stream>>>(Xh, wph, bp, nullptr, nullptr, nullptr, out, 768);
}